// Round 5
// baseline (108.690 us; speedup 1.0000x reference)
//
#include <hip/hip_runtime.h>

// out[b, t] = x[b] * r^t,  r = 1.0 + (0.99 - 1.0) * delta_t  (f64 -> f32).
// Output layout: (B, steps, 1) row-major fp32 -> out[b*steps + t].
//
// Write-BW-bound (512 MiB). Ladder: R1 4.8 TB/s; R2 4-row float4 5.54; R3
// nt-flag neutral; R4 fill-mimic low-occupancy REGRESSED (107us) -> high-TLP
// R2 structure is right. R5: (1) precompute scale[t]=r^t table (16 KiB in
// d_ws) in a tiny kernel -> kills the per-thread f64 exp2 prologue that idles
// HBM during ramp; (2) unroll the row-quad loop x2 with hoisted loads for
// deeper store pipelining.

typedef float vfloat4 __attribute__((ext_vector_type(4)));

__global__ __launch_bounds__(256) void air_res_table(
    const float* __restrict__ dt_p,
    float* __restrict__ scale,   // steps floats
    int steps)
{
    const int t = blockIdx.x * blockDim.x + threadIdx.x;
    if (t < steps) {
        const double COEF = 0.99 - 1.0;
        const double rd   = 1.0 + COEF * (double)dt_p[0];
        scale[t] = (float)exp2((double)t * log2(rd));
    }
}

__global__ __launch_bounds__(256) void air_res_vec4x4(
    const float4* __restrict__ xv,      // B/4 float4s
    const float4* __restrict__ scale4,  // steps/4 float4s (r^t table)
    float* __restrict__ out,
    int B4, int steps4)                 // B/4, steps/4
{
    const long long tid      = (long long)blockIdx.x * blockDim.x + threadIdx.x;
    const long long nthreads = (long long)gridDim.x * blockDim.x;

    // Host guarantees nthreads % steps4 == 0 -> tq invariant over the g-loop,
    // and (B4 / gstep) % 2 == 0 -> clean x2 unroll.
    int g        = (int)(tid / steps4);          // row-quad group
    const int tq = (int)(tid % steps4);
    const int gstep = (int)(nthreads / steps4);

    const float4 s = scale4[tq];                 // r^{4tq..4tq+3}, L1-resident
    const float s0 = s.x, s1 = s.y, s2 = s.z, s3 = s.w;

    const long long row_f = 4LL * steps4;        // floats per row
    for (; g < B4; g += 2 * gstep) {
        const int g2 = g + gstep;
        const float4 xa = xv[g];                 // x[4g .. 4g+3]
        const float4 xb = xv[g2];
        float* pa = out + (long long)(4 * g)  * row_f + 4LL * tq;
        float* pb = out + (long long)(4 * g2) * row_f + 4LL * tq;

        *(vfloat4*)(pa)             = (vfloat4){xa.x*s0, xa.x*s1, xa.x*s2, xa.x*s3};
        *(vfloat4*)(pa + 1*row_f)   = (vfloat4){xa.y*s0, xa.y*s1, xa.y*s2, xa.y*s3};
        *(vfloat4*)(pa + 2*row_f)   = (vfloat4){xa.z*s0, xa.z*s1, xa.z*s2, xa.z*s3};
        *(vfloat4*)(pa + 3*row_f)   = (vfloat4){xa.w*s0, xa.w*s1, xa.w*s2, xa.w*s3};
        *(vfloat4*)(pb)             = (vfloat4){xb.x*s0, xb.x*s1, xb.x*s2, xb.x*s3};
        *(vfloat4*)(pb + 1*row_f)   = (vfloat4){xb.y*s0, xb.y*s1, xb.y*s2, xb.y*s3};
        *(vfloat4*)(pb + 2*row_f)   = (vfloat4){xb.z*s0, xb.z*s1, xb.z*s2, xb.z*s3};
        *(vfloat4*)(pb + 3*row_f)   = (vfloat4){xb.w*s0, xb.w*s1, xb.w*s2, xb.w*s3};
    }
}

// Generic scalar fallback (any shape). One element per thread, grid-stride.
__global__ __launch_bounds__(256) void air_res_scalar(
    const float* __restrict__ x,
    const float* __restrict__ dt_p,
    float* __restrict__ out,
    int B, int steps)
{
    const long long total    = (long long)B * steps;
    const long long nthreads = (long long)gridDim.x * blockDim.x;
    const double COEF = 0.99 - 1.0;
    const double rd   = 1.0 + COEF * (double)dt_p[0];
    const double l2r  = log2(rd);

    for (long long i = (long long)blockIdx.x * blockDim.x + threadIdx.x;
         i < total; i += nthreads) {
        const int b = (int)(i / steps);
        const int t = (int)(i % steps);
        out[i] = x[b] * (float)exp2((double)t * l2r);
    }
}

extern "C" void kernel_launch(void* const* d_in, const int* in_sizes, int n_in,
                              void* d_out, int out_size, void* d_ws, size_t ws_size,
                              hipStream_t stream) {
    // Inputs (setup_inputs order): steps (scalar, unused on host side),
    // x (float32, B elements), delta_t (float32 scalar, on device).
    const float* x    = (const float*)d_in[1];
    const float* dt_p = (const float*)d_in[2];
    float* out        = (float*)d_out;
    float* scale      = (float*)d_ws;            // steps floats (16 KiB)

    const int B     = in_sizes[1];
    const int steps = out_size / B;   // 4096

    const int threads = 256;
    const int blocks  = 2048;         // 524288 threads, 32 waves/CU
    const long long nthreads = (long long)blocks * threads;

    const bool vec_ok =
        (steps % 4) == 0 && (B % 4) == 0 &&
        (nthreads % (steps / 4)) == 0 &&
        ((long long)(B / 4) % (2 * (nthreads / (steps / 4)))) == 0 &&
        ws_size >= (size_t)steps * sizeof(float);

    if (vec_ok) {
        air_res_table<<<(steps + 255) / 256, 256, 0, stream>>>(dt_p, scale, steps);
        air_res_vec4x4<<<blocks, threads, 0, stream>>>(
            (const float4*)x, (const float4*)scale, out, B / 4, steps / 4);
    } else {
        air_res_scalar<<<2048, threads, 0, stream>>>(x, dt_p, out, B, steps);
    }
}

// Round 6
// 95.710 us; speedup vs baseline: 1.1356x; 1.1356x over previous
//
#include <hip/hip_runtime.h>

// out[b, t] = x[b] * r^t,  r = 1.0 + (0.99 - 1.0) * delta_t  (f64 -> f32,
// matching the reference's Python-double -> f32 path).
// Output layout: (B, steps, 1) row-major fp32 -> out[b*steps + t].
//
// Write-BW-bound: 512 MiB stored. Ladder: R1 scalar 4.8 TB/s; R2 4-row float4
// + NT 5.54; R3 plain stores 5.61 (BEST); R4 fill-mimic low-occupancy 107us
// REGRESS; R5 table+unroll 108us REGRESS. The simple high-TLP structure wins:
// 2048 blocks x 256 thr (32 waves/CU), each thread owns a fixed 16B t-slot,
// strides over 4-row groups; every grid sweep writes one contiguous 8 MiB
// span. This is the empirical optimum -> exact R3 revert.

typedef float vfloat4 __attribute__((ext_vector_type(4)));

__global__ __launch_bounds__(256) void air_res_vec4x4(
    const float4* __restrict__ xv,   // B/4 float4s
    const float* __restrict__ dt_p,
    float* __restrict__ out,
    int B4, int steps4)              // B/4, steps/4
{
    const long long tid      = (long long)blockIdx.x * blockDim.x + threadIdx.x;
    const long long nthreads = (long long)gridDim.x * blockDim.x;

    // Host guarantees nthreads % steps4 == 0 -> tq invariant over the b-loop.
    int g        = (int)(tid / steps4);        // row-quad group
    const int tq = (int)(tid % steps4);
    const int gstep = (int)(nthreads / steps4);

    const double COEF = 0.99 - 1.0;            // exact reference constant
    const double rd   = 1.0 + COEF * (double)dt_p[0];
    const float  rf   = (float)rd;
    // r^(4*tq) in f64: t up to 4095 keeps the cast-to-f32 error ~1 ulp.
    const float s0 = (float)exp2((double)(4 * tq) * log2(rd));
    const float s1 = s0 * rf;
    const float s2 = s1 * rf;
    const float s3 = s2 * rf;

    for (; g < B4; g += gstep) {
        const float4 xb = xv[g];               // x[4g .. 4g+3], aligned 16B
        float* p = out + (long long)(4 * g) * (long long)(4 * steps4) + 4LL * tq;

        *(vfloat4*)p =
            (vfloat4){xb.x * s0, xb.x * s1, xb.x * s2, xb.x * s3};
        *(vfloat4*)(p + 4LL * steps4) =
            (vfloat4){xb.y * s0, xb.y * s1, xb.y * s2, xb.y * s3};
        *(vfloat4*)(p + 8LL * steps4) =
            (vfloat4){xb.z * s0, xb.z * s1, xb.z * s2, xb.z * s3};
        *(vfloat4*)(p + 12LL * steps4) =
            (vfloat4){xb.w * s0, xb.w * s1, xb.w * s2, xb.w * s3};
    }
}

// Generic scalar fallback (any shape). One element per thread, grid-stride.
__global__ __launch_bounds__(256) void air_res_scalar(
    const float* __restrict__ x,
    const float* __restrict__ dt_p,
    float* __restrict__ out,
    int B, int steps)
{
    const long long total    = (long long)B * steps;
    const long long nthreads = (long long)gridDim.x * blockDim.x;
    const double COEF = 0.99 - 1.0;
    const double rd   = 1.0 + COEF * (double)dt_p[0];
    const double l2r  = log2(rd);

    for (long long i = (long long)blockIdx.x * blockDim.x + threadIdx.x;
         i < total; i += nthreads) {
        const int b = (int)(i / steps);
        const int t = (int)(i % steps);
        out[i] = x[b] * (float)exp2((double)t * l2r);
    }
}

extern "C" void kernel_launch(void* const* d_in, const int* in_sizes, int n_in,
                              void* d_out, int out_size, void* d_ws, size_t ws_size,
                              hipStream_t stream) {
    // Inputs (setup_inputs order): steps (scalar, unused on host side),
    // x (float32, B elements), delta_t (float32 scalar, on device).
    const float* x    = (const float*)d_in[1];
    const float* dt_p = (const float*)d_in[2];
    float* out        = (float*)d_out;

    const int B     = in_sizes[1];
    const int steps = out_size / B;   // 4096

    const int threads = 256;
    const int blocks  = 2048;         // 524288 threads
    const long long nthreads = (long long)blocks * threads;

    if ((steps % 4) == 0 && (B % 4) == 0 &&
        (nthreads % (steps / 4)) == 0) {
        air_res_vec4x4<<<blocks, threads, 0, stream>>>(
            (const float4*)x, dt_p, out, B / 4, steps / 4);
    } else {
        air_res_scalar<<<2048, threads, 0, stream>>>(x, dt_p, out, B, steps);
    }
}